// Round 7
// baseline (1676.518 us; speedup 1.0000x reference)
//
#include <hip/hip_runtime.h>
#include <hip/hip_fp16.h>

// SignedGCN (2-layer, eval).
// R16: tile_sort3 + gather-agg replaced by LDS-scatter aggregation.
// Rationale: segment sum is order-independent -> within-bucket dst sort is
// unnecessary if agg scatters into a per-bucket LDS accumulator
// (256 nodes x 16 f32 = 16 KB). agg_scatter streams the bucket's pairs
// (coalesced), gathers tab[src] (same random-gather pattern = proven ~48us
// MSHR floor), ds_add_f32 into LDS (4 insts / 16 edges / wave ~ 5us).
// Eliminates: tile_sort3 (51MB reads + 25.6M LDS atomics + 25.6MB srcs
// write) and the srcs/row arrays. deg for dinv = global atomics riding
// bucket_count2's existing dst read; consumers compute rsqrt(1+deg) inline.
// Build (count/col_scan/fill) and xw1/combine1/final2 otherwise = R15.

#define BSHIFT 8
#define BSZ 256
#define MAX_NBK 512
#define FILL_CAP 13056      // max edges per chunk staged in LDS (51 KB)

typedef int   i32x4 __attribute__((ext_vector_type(4)));

__device__ __forceinline__ int chunk_of_block(int bid, int NCH) {
  return (NCH % 8 == 0) ? (bid % 8) * (NCH / 8) + bid / 8 : bid;
}

// ---- build: edges bucketed by dst>>8 (+ per-node degree count) ----

__global__ __launch_bounds__(256) void bucket_count2(
    const int* __restrict__ eP, const int* __restrict__ eN,
    int E, int CH, int NCH, int NBK, int* __restrict__ ccP, int* __restrict__ ccN,
    int* __restrict__ deg, int n) {
  __shared__ int cnt[MAX_NBK];
  const int* dsts = (blockIdx.y ? eN : eP) + E;
  int* cc = blockIdx.y ? ccN : ccP;
  int* dg = deg + (size_t)blockIdx.y * n;
  const int c = chunk_of_block(blockIdx.x, NCH);
  for (int i = threadIdx.x; i < NBK; i += 256) cnt[i] = 0;
  __syncthreads();
  int base = c * CH, end = min(E, base + CH);
  for (int idx = base + threadIdx.x * 4; idx < end; idx += 1024) {
    if (idx + 4 <= end) {
      i32x4 d = __builtin_nontemporal_load((const i32x4*)(dsts + idx));
      atomicAdd(&cnt[d.x >> BSHIFT], 1);
      atomicAdd(&cnt[d.y >> BSHIFT], 1);
      atomicAdd(&cnt[d.z >> BSHIFT], 1);
      atomicAdd(&cnt[d.w >> BSHIFT], 1);
      atomicAdd(&dg[d.x], 1);
      atomicAdd(&dg[d.y], 1);
      atomicAdd(&dg[d.z], 1);
      atomicAdd(&dg[d.w], 1);
    } else {
      for (int k = idx; k < end; ++k) {
        atomicAdd(&cnt[dsts[k] >> BSHIFT], 1);
        atomicAdd(&dg[dsts[k]], 1);
      }
    }
  }
  __syncthreads();
  for (int i = threadIdx.x; i < NBK; i += 256)
    cc[(size_t)c * NBK + i] = cnt[i];
}

__global__ __launch_bounds__(512) void col_scan2(
    int* __restrict__ ccP, int* __restrict__ ccN, int NCH, int NBK,
    int* __restrict__ totP, int* __restrict__ totN) {
  __shared__ int s[512];
  int* cc = blockIdx.y ? ccN : ccP;
  int* tot = blockIdx.y ? totN : totP;
  int b = blockIdx.x, t = threadIdx.x;
  int v = (t < NCH) ? cc[(size_t)t * NBK + b] : 0;
  s[t] = v;
  for (int off = 1; off < 512; off <<= 1) {
    __syncthreads();
    int a = (t >= off) ? s[t - off] : 0;
    __syncthreads();
    s[t] += a;
  }
  __syncthreads();
  if (t < NCH) cc[(size_t)t * NBK + b] = s[t] - v;
  if (t == 511) tot[b] = s[511];
}

// fill: computes global bucket bases (exclusive scan of tot) in-LDS.
__global__ __launch_bounds__(512) void bucket_fill3(
    const int* __restrict__ eP, const int* __restrict__ eN,
    int E, int CH, int NCH, int NBK,
    const int* __restrict__ ccP, const int* __restrict__ ccN,
    const int* __restrict__ totP, const int* __restrict__ totN,
    unsigned* __restrict__ prP, unsigned* __restrict__ prN) {
  __shared__ unsigned obuf[FILL_CAP];
  __shared__ int chofs[MAX_NBK], hist[MAX_NBK], lofs[MAX_NBK], cur[MAX_NBK];
  __shared__ int bas_l[MAX_NBK];
  __shared__ int s[512];
  const int* edges = blockIdx.y ? eN : eP;
  const int* cc = blockIdx.y ? ccN : ccP;
  const int* tot = blockIdx.y ? totN : totP;
  unsigned* pairs = blockIdx.y ? prN : prP;
  const int c = chunk_of_block(blockIdx.x, NCH);
  const int t = threadIdx.x;

  int h = 0;
  if (t < NBK) {
    int o0 = cc[(size_t)c * NBK + t];
    int o1 = (c + 1 < NCH) ? cc[(size_t)(c + 1) * NBK + t] : tot[t];
    chofs[t] = o0;
    h = o1 - o0;
    hist[t] = h;
  }
  s[t] = h;
  for (int off = 1; off < 512; off <<= 1) {
    __syncthreads();
    int a = (t >= off) ? s[t - off] : 0;
    __syncthreads();
    s[t] += a;
  }
  __syncthreads();
  if (t < NBK) { lofs[t] = s[t] - hist[t]; cur[t] = s[t] - hist[t]; }
  __syncthreads();

  // in-block exclusive scan of tot -> global bucket bases
  int tv = (t < NBK) ? tot[t] : 0;
  s[t] = tv;
  for (int off = 1; off < 512; off <<= 1) {
    __syncthreads();
    int a = (t >= off) ? s[t - off] : 0;
    __syncthreads();
    s[t] += a;
  }
  __syncthreads();
  if (t < NBK) bas_l[t] = s[t] - tv;
  __syncthreads();

  int base = c * CH, end = min(E, base + CH);
  for (int idx = base + t * 4; idx < end; idx += 2048) {
    if (idx + 4 <= end) {
      i32x4 sv = __builtin_nontemporal_load((const i32x4*)(edges + idx));
      i32x4 dv = __builtin_nontemporal_load((const i32x4*)(edges + E + idx));
      int p0 = atomicAdd(&cur[dv.x >> BSHIFT], 1);
      obuf[p0] = (unsigned)sv.x | ((unsigned)(dv.x & (BSZ - 1)) << 24);
      int p1 = atomicAdd(&cur[dv.y >> BSHIFT], 1);
      obuf[p1] = (unsigned)sv.y | ((unsigned)(dv.y & (BSZ - 1)) << 24);
      int p2 = atomicAdd(&cur[dv.z >> BSHIFT], 1);
      obuf[p2] = (unsigned)sv.z | ((unsigned)(dv.z & (BSZ - 1)) << 24);
      int p3 = atomicAdd(&cur[dv.w >> BSHIFT], 1);
      obuf[p3] = (unsigned)sv.w | ((unsigned)(dv.w & (BSZ - 1)) << 24);
    } else {
      for (int k = idx; k < end; ++k) {
        int sv = edges[k], d = edges[E + k];
        int pos = atomicAdd(&cur[d >> BSHIFT], 1);
        obuf[pos] = (unsigned)sv | ((unsigned)(d & (BSZ - 1)) << 24);
      }
    }
  }
  __syncthreads();

  // wave-cooperative coalesced copy-out (one wave per bucket, round-robin)
  const int wv = t >> 6, ln = t & 63;
  for (int b = wv; b < NBK; b += 8) {
    int cnt2 = hist[b], lo = lofs[b];
    unsigned* dst = pairs + (size_t)bas_l[b] + chofs[b];
    for (int j = ln; j < cnt2; j += 64) dst[j] = obuf[lo + j];
  }
}

// x: [n,128] @ W{p,n}: [128,16] -> hs{p,n}: [n,16] fp16 (scaled by dinv[i])
__global__ __launch_bounds__(256) void xw1_kernel(
    const float* __restrict__ x, const float* __restrict__ Wp, const float* __restrict__ Wn,
    const int* __restrict__ degP, const int* __restrict__ degN,
    __half* __restrict__ hp, __half* __restrict__ hn, int n)
{
  __shared__ float xs[16 * 132];
  __shared__ float wp[128 * 16], wn[128 * 16];
  const int tid = threadIdx.x;
  const int rowBase = blockIdx.x * 16;

  for (int idx = tid; idx < 512; idx += 256) {
    ((float4*)wp)[idx] = ((const float4*)Wp)[idx];
    ((float4*)wn)[idx] = ((const float4*)Wn)[idx];
  }
  const int nrows = min(16, n - rowBase);
  for (int idx = tid; idx < nrows * 32; idx += 256) {
    int r = idx >> 5, c4 = idx & 31;
    float4 v = ((const float4*)(x + (size_t)(rowBase + r) * 128))[c4];
    *(float4*)(xs + r * 132 + c4 * 4) = v;
  }
  __syncthreads();

  const int r = tid >> 4, c = tid & 15;
  const int i = rowBase + r;
  if (i < n) {
    float ap = 0.f, an = 0.f;
    #pragma unroll
    for (int k = 0; k < 128; ++k) {
      float xv = xs[r * 132 + k];
      ap += xv * wp[k * 16 + c];
      an += xv * wn[k * 16 + c];
    }
    float dp = rsqrtf(1.0f + (float)degP[i]);
    float dn = rsqrtf(1.0f + (float)degN[i]);
    hp[(size_t)i * 16 + c] = __float2half(ap * dp);
    hn[(size_t)i * 16 + c] = __float2half(an * dn);
  }
}

// LDS-scatter aggregation. One block per (bucket, sign); blockIdx%8 -> XCD
// (XCD 0-3 pos / 4-7 neg) keeps each sign's 3.2 MB table in its XCD L2.
// Streams the bucket's pairs (coalesced), gathers tab[src] rows (4 lanes x
// uint2 = one 32B line request per edge, same pattern as the proven gather),
// ds_add_f32 into acc[256][16]. Epilogue adds self row, scales by dinv.
__global__ __launch_bounds__(512) void agg_scatter(
    const unsigned* __restrict__ prP, const unsigned* __restrict__ prN,
    const int* __restrict__ totP, const int* __restrict__ totN,
    const __half* __restrict__ inP, const __half* __restrict__ inN,
    const int* __restrict__ degP, const int* __restrict__ degN,
    float* __restrict__ tmpP, float* __restrict__ tmpN, int n, int NBK)
{
  __shared__ float acc[BSZ * 16];      // 16 KB
  __shared__ int red[512];
  const int gb = blockIdx.x;
  const int xcd = gb & 7;
  const int sign = xcd >> 2;
  const int bkt = (gb >> 3) * 4 + (xcd & 3);
  if (bkt >= NBK) return;
  const int tid = threadIdx.x;

  const unsigned* __restrict__ pairs = sign ? prN : prP;
  const int* __restrict__ tot = sign ? totN : totP;
  const __half* __restrict__ tab = sign ? inN : inP;
  const int* __restrict__ dg = sign ? degN : degP;
  float* __restrict__ tmp = sign ? tmpN : tmpP;

  // bucket base = sum(tot[0..bkt)) ; zero the accumulator
  int part = 0;
  for (int j = tid; j < bkt; j += 512) part += tot[j];
  red[tid] = part;
  for (int i = tid; i < BSZ * 16; i += 512) acc[i] = 0.f;
  __syncthreads();
  for (int off = 256; off > 0; off >>= 1) {
    if (tid < off) red[tid] += red[tid + off];
    __syncthreads();
  }
  const int s0 = red[0];
  const int s1 = s0 + tot[bkt];

  // scatter: 4 lanes per edge, unroll-8 (8 gathers in flight per lane)
  const int egrp = tid >> 2, lane4 = tid & 3;
  int e = s0 + egrp;
  for (; e + 896 < s1; e += 1024) {
    unsigned p[8];
    #pragma unroll
    for (int j = 0; j < 8; ++j) p[j] = pairs[e + j * 128];
    uint2 v[8];
    #pragma unroll
    for (int j = 0; j < 8; ++j)
      v[j] = *(const uint2*)(tab + (size_t)(p[j] & 0xFFFFFFu) * 16 + lane4 * 4);
    #pragma unroll
    for (int j = 0; j < 8; ++j) {
      float* a = acc + ((p[j] >> 24) * 16 + lane4 * 4);
      float2 f01 = __half22float2(*(const __half2*)&v[j].x);
      float2 f23 = __half22float2(*(const __half2*)&v[j].y);
      atomicAdd(a + 0, f01.x);
      atomicAdd(a + 1, f01.y);
      atomicAdd(a + 2, f23.x);
      atomicAdd(a + 3, f23.y);
    }
  }
  for (; e < s1; e += 128) {
    unsigned p = pairs[e];
    uint2 v = *(const uint2*)(tab + (size_t)(p & 0xFFFFFFu) * 16 + lane4 * 4);
    float* a = acc + ((p >> 24) * 16 + lane4 * 4);
    float2 f01 = __half22float2(*(const __half2*)&v.x);
    float2 f23 = __half22float2(*(const __half2*)&v.y);
    atomicAdd(a + 0, f01.x);
    atomicAdd(a + 1, f01.y);
    atomicAdd(a + 2, f23.x);
    atomicAdd(a + 3, f23.y);
  }
  __syncthreads();

  // epilogue: tmp[i] = dinv[i] * (acc[i] + self_row[i]); coalesced float4x2
  const int node = tid >> 1, half = tid & 1;
  const int gnode = bkt * BSZ + node;
  if (gnode < n) {
    const float d = rsqrtf(1.0f + (float)dg[gnode]);
    uint4 sv = *(const uint4*)(tab + (size_t)gnode * 16 + half * 8);
    const __half2* hh = (const __half2*)&sv;
    float2 s01 = __half22float2(hh[0]);
    float2 s23 = __half22float2(hh[1]);
    float2 s45 = __half22float2(hh[2]);
    float2 s67 = __half22float2(hh[3]);
    const float* ap = acc + node * 16 + half * 8;
    float4 o0, o1;
    o0.x = (ap[0] + s01.x) * d; o0.y = (ap[1] + s01.y) * d;
    o0.z = (ap[2] + s23.x) * d; o0.w = (ap[3] + s23.y) * d;
    o1.x = (ap[4] + s45.x) * d; o1.y = (ap[5] + s45.y) * d;
    o1.z = (ap[6] + s67.x) * d; o1.w = (ap[7] + s67.y) * d;
    *(float4*)(tmp + (size_t)gnode * 16 + half * 8) = o0;
    *(float4*)(tmp + (size_t)gnode * 16 + half * 8 + 4) = o1;
  }
}

// layer-1 combine: h = relu(b+tmpP) - relu(b+tmpN); G{p,n} = h*dinv fp16
__global__ __launch_bounds__(256) void combine1(
    const float* __restrict__ tmpP, const float* __restrict__ tmpN,
    const float* __restrict__ bp, const float* __restrict__ bn,
    const int* __restrict__ degP, const int* __restrict__ degN,
    __half* __restrict__ Gp, __half* __restrict__ Gn, int nq)
{
  int q = blockIdx.x * 256 + threadIdx.x;
  if (q >= nq) return;
  int i = q >> 2;
  float4 tp = ((const float4*)tmpP)[q];
  float4 tn = ((const float4*)tmpN)[q];
  float4 bpv = ((const float4*)bp)[q & 3];
  float4 bnv = ((const float4*)bn)[q & 3];
  float dp = rsqrtf(1.0f + (float)degP[i]);
  float dn = rsqrtf(1.0f + (float)degN[i]);
  float h0 = fmaxf(bpv.x + tp.x, 0.f) - fmaxf(bnv.x + tn.x, 0.f);
  float h1 = fmaxf(bpv.y + tp.y, 0.f) - fmaxf(bnv.y + tn.y, 0.f);
  float h2 = fmaxf(bpv.z + tp.z, 0.f) - fmaxf(bnv.z + tn.z, 0.f);
  float h3 = fmaxf(bpv.w + tp.w, 0.f) - fmaxf(bnv.w + tn.w, 0.f);
  union { uint2 u; __half2 h[2]; } a, b;
  a.h[0] = __floats2half2_rn(h0 * dp, h1 * dp);
  a.h[1] = __floats2half2_rn(h2 * dp, h3 * dp);
  b.h[0] = __floats2half2_rn(h0 * dn, h1 * dn);
  b.h[1] = __floats2half2_rn(h2 * dn, h3 * dn);
  ((uint2*)Gp)[q] = a.u;
  ((uint2*)Gn)[q] = b.u;
}

// layer-2 epilogue: W2 GEMM + bias + relu-combine + log_softmax
__global__ __launch_bounds__(256) void final2(
    const float* __restrict__ Up, const float* __restrict__ Un,
    const float* __restrict__ W2p, const float* __restrict__ W2n,
    const float* __restrict__ b2p, const float* __restrict__ b2n,
    float* __restrict__ out, int n)
{
  __shared__ float wp[16 * 32], wn[16 * 32];
  for (int i = threadIdx.x; i < 512; i += 256) { wp[i] = W2p[i]; wn[i] = W2n[i]; }
  __syncthreads();

  const int tid = threadIdx.x;
  const int lane = tid & 15, grp = tid >> 4;
  const int i = blockIdx.x * 16 + grp;
  if (i >= n) return;

  float tp = Up[(size_t)i * 16 + lane];
  float tn = Un[(size_t)i * 16 + lane];

  float ap0 = b2p[lane], ap1 = b2p[lane + 16];
  float an0 = b2n[lane], an1 = b2n[lane + 16];
  #pragma unroll
  for (int k = 0; k < 16; ++k) {
    float tpk = __shfl(tp, k, 16);
    float tnk = __shfl(tn, k, 16);
    ap0 += tpk * wp[k * 32 + lane];
    ap1 += tpk * wp[k * 32 + lane + 16];
    an0 += tnk * wn[k * 32 + lane];
    an1 += tnk * wn[k * 32 + lane + 16];
  }
  float v0 = fmaxf(ap0, 0.f) - fmaxf(an0, 0.f);
  float v1 = fmaxf(ap1, 0.f) - fmaxf(an1, 0.f);
  float m = fmaxf(v0, v1);
  #pragma unroll
  for (int off = 8; off > 0; off >>= 1) m = fmaxf(m, __shfl_xor(m, off, 16));
  float s = __expf(v0 - m) + __expf(v1 - m);
  #pragma unroll
  for (int off = 8; off > 0; off >>= 1) s += __shfl_xor(s, off, 16);
  float ls = __logf(s);
  out[(size_t)i * 32 + lane] = v0 - m - ls;
  out[(size_t)i * 32 + lane + 16] = v1 - m - ls;
}

extern "C" void kernel_launch(void* const* d_in, const int* in_sizes, int n_in,
                              void* d_out, int out_size, void* d_ws, size_t ws_size,
                              hipStream_t stream) {
  const float* x   = (const float*)d_in[0];
  const int*   eP  = (const int*)d_in[1];
  const int*   eN  = (const int*)d_in[2];
  const float* W1p = (const float*)d_in[3];
  const float* b1p = (const float*)d_in[4];
  const float* W1n = (const float*)d_in[5];
  const float* b1n = (const float*)d_in[6];
  const float* W2p = (const float*)d_in[7];
  const float* b2p = (const float*)d_in[8];
  const float* W2n = (const float*)d_in[9];
  const float* b2n = (const float*)d_in[10];
  float* out = (float*)d_out;

  const int HID = in_sizes[4];             // 16
  const int F   = in_sizes[3] / HID;       // 128
  const int n   = in_sizes[0] / F;         // 100000
  const int E   = in_sizes[1] / 2;         // 3,200,000
  (void)out_size; (void)n_in; (void)ws_size;

  const int NBK = (n + BSZ - 1) >> BSHIFT;                 // 391
  const int CH  = (((E + 255) / 256) + 255) & ~255;        // 12544
  const int NCH = (E + CH - 1) / CH;                       // 256

  char* p = (char*)d_ws;
  auto alloc = [&](size_t bytes) { char* r = p; p += (bytes + 255) & ~(size_t)255; return r; };

  int*      ccP   = (int*)alloc((size_t)NCH * NBK * 4);
  int*      ccN   = (int*)alloc((size_t)NCH * NBK * 4);
  int*      totP  = (int*)alloc((size_t)NBK * 4);
  int*      totN  = (int*)alloc((size_t)NBK * 4);
  unsigned* prP   = (unsigned*)alloc((size_t)E * 4);
  unsigned* prN   = (unsigned*)alloc((size_t)E * 4);
  int*      deg   = (int*)alloc((size_t)2 * n * 4);        // degP | degN
  __half*   hsP   = (__half*)alloc((size_t)n * 16 * 2);
  __half*   hsN   = (__half*)alloc((size_t)n * 16 * 2);
  __half*   Gp    = (__half*)alloc((size_t)n * 16 * 2);
  __half*   Gn    = (__half*)alloc((size_t)n * 16 * 2);
  float*    tmpP  = (float*)alloc((size_t)n * 16 * 4);
  float*    tmpN  = (float*)alloc((size_t)n * 16 * 4);
  int*      degP  = deg;
  int*      degN  = deg + n;

  // ---- build: bucket pairs + per-node degree ----
  hipMemsetAsync(deg, 0, (size_t)2 * n * 4, stream);
  hipLaunchKernelGGL(bucket_count2, dim3(NCH, 2), dim3(256), 0, stream,
                     eP, eN, E, CH, NCH, NBK, ccP, ccN, deg, n);
  hipLaunchKernelGGL(col_scan2, dim3(NBK, 2), dim3(512), 0, stream,
                     ccP, ccN, NCH, NBK, totP, totN);
  hipLaunchKernelGGL(bucket_fill3, dim3(NCH, 2), dim3(512), 0, stream,
                     eP, eN, E, CH, NCH, NBK, ccP, ccN, totP, totN, prP, prN);

  // grids
  const int NB16 = (n + 15) / 16;                 // 6250 (xw1/final2)
  const int NBS  = ((NBK + 3) / 4) * 4;           // 392
  const int GRID = NBS * 2;                       // 784 (multiple of 8)

  // ---- layer 1 ----
  hipLaunchKernelGGL(xw1_kernel, dim3(NB16), dim3(256), 0, stream,
                     x, W1p, W1n, degP, degN, hsP, hsN, n);
  hipLaunchKernelGGL(agg_scatter, dim3(GRID), dim3(512), 0, stream,
                     prP, prN, totP, totN, hsP, hsN, degP, degN, tmpP, tmpN, n, NBK);
  hipLaunchKernelGGL(combine1, dim3((n * 4 + 255) / 256), dim3(256), 0, stream,
                     tmpP, tmpN, b1p, b1n, degP, degN, Gp, Gn, n * 4);

  // ---- layer 2 ----
  hipLaunchKernelGGL(agg_scatter, dim3(GRID), dim3(512), 0, stream,
                     prP, prN, totP, totN, Gp, Gn, degP, degN, tmpP, tmpN, n, NBK);
  hipLaunchKernelGGL(final2, dim3(NB16), dim3(256), 0, stream,
                     tmpP, tmpN, W2p, W2n, b2p, b2n, out, n);
}

// Round 8
// 227.369 us; speedup vs baseline: 7.3735x; 7.3735x over previous
//
#include <hip/hip_runtime.h>
#include <hip/hip_fp16.h>

// SignedGCN (2-layer, eval) — dst-sorted segment gather, register accumulation.
// R17: R15 (238.8us, proven) + conservative build tweaks:
//  - CH 12544->6252 (NCH 512): bucket_fill3 LDS 61->37KB -> 4 blocks/CU (2x
//    latency cover for its pos-claim LDS atomics); copy-out in 32-lane groups.
//  - bucket_count2: 2-way sub-histogram cnt[b][t&1] (adjacent banks) halves
//    within-wave same-address atomic replays.
//  - tile_sort3: 4-way sub-histogram hist4[key][t&3]; SORT_CAP 10240 (keeps
//    3 blocks/CU; >CAP fallback preserves correctness); hist-pass loads PLAIN
//    (so pass 2 hits cache), scatter-pass loads nt (last use).
// agg_split / xw1 / combine1 / final2: byte-exact R15 (agg at MSHR*latency
// floor ~47.5us; R11/R12/R13/R14/R16 alternatives all regressed).

#define BSHIFT 8
#define BSZ 256
#define MAX_NBK 512
#define FILL_CAP 6272       // max edges per chunk staged in LDS (24.5 KB); >= CH
#define SORT_CAP 10240      // max edges per bucket staged in LDS (40 KB)

typedef int   i32x4 __attribute__((ext_vector_type(4)));

__device__ __forceinline__ int chunk_of_block(int bid, int NCH) {
  return (NCH % 8 == 0) ? (bid % 8) * (NCH / 8) + bid / 8 : bid;
}

// ---- build: edges bucketed by dst>>8, then counting-sorted by local dst ----

__global__ __launch_bounds__(256) void bucket_count2(
    const int* __restrict__ eP, const int* __restrict__ eN,
    int E, int CH, int NCH, int NBK, int* __restrict__ ccP, int* __restrict__ ccN) {
  __shared__ int cnt[MAX_NBK][2];          // 2-way sub-hist: halves same-addr replay
  const int* dsts = (blockIdx.y ? eN : eP) + E;
  int* cc = blockIdx.y ? ccN : ccP;
  const int c = chunk_of_block(blockIdx.x, NCH);
  for (int i = threadIdx.x; i < NBK * 2; i += 256) ((int*)cnt)[i] = 0;
  __syncthreads();
  const int sub = threadIdx.x & 1;
  int base = c * CH, end = min(E, base + CH);
  for (int idx = base + threadIdx.x * 4; idx < end; idx += 1024) {
    if (idx + 4 <= end) {
      i32x4 d = __builtin_nontemporal_load((const i32x4*)(dsts + idx));
      atomicAdd(&cnt[d.x >> BSHIFT][sub], 1);
      atomicAdd(&cnt[d.y >> BSHIFT][sub], 1);
      atomicAdd(&cnt[d.z >> BSHIFT][sub], 1);
      atomicAdd(&cnt[d.w >> BSHIFT][sub], 1);
    } else {
      for (int k = idx; k < end; ++k) atomicAdd(&cnt[dsts[k] >> BSHIFT][sub], 1);
    }
  }
  __syncthreads();
  for (int i = threadIdx.x; i < NBK; i += 256)
    cc[(size_t)c * NBK + i] = cnt[i][0] + cnt[i][1];
}

__global__ __launch_bounds__(512) void col_scan2(
    int* __restrict__ ccP, int* __restrict__ ccN, int NCH, int NBK,
    int* __restrict__ totP, int* __restrict__ totN) {
  __shared__ int s[512];
  int* cc = blockIdx.y ? ccN : ccP;
  int* tot = blockIdx.y ? totN : totP;
  int b = blockIdx.x, t = threadIdx.x;
  int v = (t < NCH) ? cc[(size_t)t * NBK + b] : 0;
  s[t] = v;
  for (int off = 1; off < 512; off <<= 1) {
    __syncthreads();
    int a = (t >= off) ? s[t - off] : 0;
    __syncthreads();
    s[t] += a;
  }
  __syncthreads();
  if (t < NCH) cc[(size_t)t * NBK + b] = s[t] - v;
  if (t == 511) tot[b] = s[511];
}

// fill: computes global bucket bases (exclusive scan of tot) in-LDS.
__global__ __launch_bounds__(512) void bucket_fill3(
    const int* __restrict__ eP, const int* __restrict__ eN,
    int E, int CH, int NCH, int NBK,
    const int* __restrict__ ccP, const int* __restrict__ ccN,
    const int* __restrict__ totP, const int* __restrict__ totN,
    unsigned* __restrict__ prP, unsigned* __restrict__ prN) {
  __shared__ unsigned obuf[FILL_CAP];
  __shared__ int chofs[MAX_NBK], hist[MAX_NBK], lofs[MAX_NBK], cur[MAX_NBK];
  __shared__ int bas_l[MAX_NBK];
  __shared__ int s[512];
  const int* edges = blockIdx.y ? eN : eP;
  const int* cc = blockIdx.y ? ccN : ccP;
  const int* tot = blockIdx.y ? totN : totP;
  unsigned* pairs = blockIdx.y ? prN : prP;
  const int c = chunk_of_block(blockIdx.x, NCH);
  const int t = threadIdx.x;

  int h = 0;
  if (t < NBK) {
    int o0 = cc[(size_t)c * NBK + t];
    int o1 = (c + 1 < NCH) ? cc[(size_t)(c + 1) * NBK + t] : tot[t];
    chofs[t] = o0;
    h = o1 - o0;
    hist[t] = h;
  }
  s[t] = h;
  for (int off = 1; off < 512; off <<= 1) {
    __syncthreads();
    int a = (t >= off) ? s[t - off] : 0;
    __syncthreads();
    s[t] += a;
  }
  __syncthreads();
  if (t < NBK) { lofs[t] = s[t] - hist[t]; cur[t] = s[t] - hist[t]; }
  __syncthreads();

  // in-block exclusive scan of tot -> global bucket bases
  int tv = (t < NBK) ? tot[t] : 0;
  s[t] = tv;
  for (int off = 1; off < 512; off <<= 1) {
    __syncthreads();
    int a = (t >= off) ? s[t - off] : 0;
    __syncthreads();
    s[t] += a;
  }
  __syncthreads();
  if (t < NBK) bas_l[t] = s[t] - tv;
  __syncthreads();

  int base = c * CH, end = min(E, base + CH);
  for (int idx = base + t * 4; idx < end; idx += 2048) {
    if (idx + 4 <= end) {
      i32x4 sv = __builtin_nontemporal_load((const i32x4*)(edges + idx));
      i32x4 dv = __builtin_nontemporal_load((const i32x4*)(edges + E + idx));
      int p0 = atomicAdd(&cur[dv.x >> BSHIFT], 1);
      obuf[p0] = (unsigned)sv.x | ((unsigned)(dv.x & (BSZ - 1)) << 24);
      int p1 = atomicAdd(&cur[dv.y >> BSHIFT], 1);
      obuf[p1] = (unsigned)sv.y | ((unsigned)(dv.y & (BSZ - 1)) << 24);
      int p2 = atomicAdd(&cur[dv.z >> BSHIFT], 1);
      obuf[p2] = (unsigned)sv.z | ((unsigned)(dv.z & (BSZ - 1)) << 24);
      int p3 = atomicAdd(&cur[dv.w >> BSHIFT], 1);
      obuf[p3] = (unsigned)sv.w | ((unsigned)(dv.w & (BSZ - 1)) << 24);
    } else {
      for (int k = idx; k < end; ++k) {
        int sv = edges[k], d = edges[E + k];
        int pos = atomicAdd(&cur[d >> BSHIFT], 1);
        obuf[pos] = (unsigned)sv | ((unsigned)(d & (BSZ - 1)) << 24);
      }
    }
  }
  __syncthreads();

  // 32-lane-group coalesced copy-out (runs are ~16 edges at CH=6252)
  const int wv = t >> 5, ln = t & 31;
  for (int b = wv; b < NBK; b += 16) {
    int cnt2 = hist[b], lo = lofs[b];
    unsigned* dst = pairs + (size_t)bas_l[b] + chofs[b];
    for (int j = ln; j < cnt2; j += 32) dst[j] = obuf[lo + j];
  }
}

// sort: computes its bucket base via in-block reduction of tot[0..b).
__global__ __launch_bounds__(256) void tile_sort3(
    const unsigned* __restrict__ prP, const unsigned* __restrict__ prN,
    const int* __restrict__ totP, const int* __restrict__ totN, int n, int E,
    float* __restrict__ dinvP, float* __restrict__ dinvN,
    int* __restrict__ rowP, int* __restrict__ rowN,
    unsigned* __restrict__ srcsP, unsigned* __restrict__ srcsN) {
  __shared__ unsigned obuf[SORT_CAP];
  __shared__ int hist4[BSZ][4];            // 4-way sub-hist by t&3
  __shared__ int scn[BSZ];
  __shared__ int cur[BSZ];
  __shared__ int red[256];
  const unsigned* pairs = blockIdx.y ? prN : prP;
  const int* tot = blockIdx.y ? totN : totP;
  float* dinv = blockIdx.y ? dinvN : dinvP;
  int* rowoff = blockIdx.y ? rowN : rowP;
  unsigned* srcs = blockIdx.y ? srcsN : srcsP;
  const int b = blockIdx.x, t = threadIdx.x;

  int part = 0;
  for (int j = t; j < b; j += 256) part += tot[j];
  red[t] = part;
  for (int i = t; i < BSZ * 4; i += 256) ((int*)hist4)[i] = 0;
  __syncthreads();
  for (int off = 128; off > 0; off >>= 1) {
    if (t < off) red[t] += red[t + off];
    __syncthreads();
  }
  const int s0 = red[0];
  const int cnt = tot[b];
  const int s1 = s0 + cnt;
  if (b == (int)gridDim.x - 1 && t == 0) rowoff[n] = E;

  const int sub = t & 3;
  for (int i = s0 + t; i < s1; i += 256)
    atomicAdd(&hist4[pairs[i] >> 24][sub], 1);       // PLAIN load: cache for pass 2
  __syncthreads();
  const int h = hist4[t][0] + hist4[t][1] + hist4[t][2] + hist4[t][3];
  scn[t] = h;
  __syncthreads();
  for (int off = 1; off < BSZ; off <<= 1) {
    int v = (t >= off) ? scn[t - off] : 0;
    __syncthreads();
    scn[t] += v;
    __syncthreads();
  }
  {
    int excl = scn[t] - h;
    cur[t] = excl;
    int node = b * BSZ + t;
    if (node < n) {
      rowoff[node] = s0 + excl;
      dinv[node] = rsqrtf(1.0f + (float)h);
    }
  }
  __syncthreads();
  if (cnt <= SORT_CAP) {
    for (int i = s0 + t; i < s1; i += 256) {
      unsigned p = __builtin_nontemporal_load(pairs + i);   // last use
      int pos = atomicAdd(&cur[p >> 24], 1);
      obuf[pos] = p & 0xFFFFFFu;
    }
    __syncthreads();
    for (int i = t; i < cnt; i += 256) srcs[s0 + i] = obuf[i];
  } else {
    for (int i = s0 + t; i < s1; i += 256) {
      unsigned p = __builtin_nontemporal_load(pairs + i);
      int pos = atomicAdd(&cur[p >> 24], 1);
      srcs[s0 + pos] = p & 0xFFFFFFu;
    }
  }
}

// x: [n,128] @ W{p,n}: [128,16] -> hs{p,n}: [n,16] fp16 (scaled by dinv[i])
__global__ __launch_bounds__(256) void xw1_kernel(
    const float* __restrict__ x, const float* __restrict__ Wp, const float* __restrict__ Wn,
    const float* __restrict__ dinvP, const float* __restrict__ dinvN,
    __half* __restrict__ hp, __half* __restrict__ hn, int n)
{
  __shared__ float xs[16 * 132];
  __shared__ float wp[128 * 16], wn[128 * 16];
  const int tid = threadIdx.x;
  const int rowBase = blockIdx.x * 16;

  for (int idx = tid; idx < 512; idx += 256) {
    ((float4*)wp)[idx] = ((const float4*)Wp)[idx];
    ((float4*)wn)[idx] = ((const float4*)Wn)[idx];
  }
  const int nrows = min(16, n - rowBase);
  for (int idx = tid; idx < nrows * 32; idx += 256) {
    int r = idx >> 5, c4 = idx & 31;
    float4 v = ((const float4*)(x + (size_t)(rowBase + r) * 128))[c4];
    *(float4*)(xs + r * 132 + c4 * 4) = v;
  }
  __syncthreads();

  const int r = tid >> 4, c = tid & 15;
  const int i = rowBase + r;
  if (i < n) {
    float ap = 0.f, an = 0.f;
    #pragma unroll
    for (int k = 0; k < 128; ++k) {
      float xv = xs[r * 132 + k];
      ap += xv * wp[k * 16 + c];
      an += xv * wn[k * 16 + c];
    }
    hp[(size_t)i * 16 + c] = __float2half(ap * dinvP[i]);
    hn[(size_t)i * 16 + c] = __float2half(an * dinvN[i]);
  }
}

// fused f16->f32 convert + accumulate: acc += (float)h  (one VALU op each)
__device__ __forceinline__ void fma_mix2(float& aLo, float& aHi, unsigned h2, float one) {
  asm("v_fma_mix_f32 %0, %2, %3, %0 op_sel:[0,0,0] op_sel_hi:[1,0,0]\n\t"
      "v_fma_mix_f32 %1, %2, %3, %1 op_sel:[1,0,0] op_sel_hi:[1,0,0]"
      : "+v"(aLo), "+v"(aHi)
      : "v"(h2), "v"(one));
}

// unroll-8, two accumulator chains (R10: plain loads, L1 serves index lines)
__device__ __forceinline__ void seg_sum4(
    const unsigned* __restrict__ srcs, int e, int e1,
    const __half* __restrict__ tab, int lane4, float one,
    float& f0, float& f1, float& f2, float& f3)
{
  float g0 = 0.f, g1 = 0.f, g2 = 0.f, g3 = 0.f;
  for (; e + 8 <= e1; e += 8) {
    unsigned a[8];
    #pragma unroll
    for (int j = 0; j < 8; ++j) a[j] = srcs[e + j];
    uint2 v[8];
    #pragma unroll
    for (int j = 0; j < 8; ++j)
      v[j] = *(const uint2*)(tab + (size_t)a[j] * 16 + lane4 * 4);
    #pragma unroll
    for (int j = 0; j < 8; j += 2) {
      fma_mix2(f0, f1, v[j].x, one);
      fma_mix2(f2, f3, v[j].y, one);
      fma_mix2(g0, g1, v[j + 1].x, one);
      fma_mix2(g2, g3, v[j + 1].y, one);
    }
  }
  for (; e + 2 <= e1; e += 2) {
    unsigned a0 = srcs[e], a1 = srcs[e + 1];
    uint2 v0 = *(const uint2*)(tab + (size_t)a0 * 16 + lane4 * 4);
    uint2 v1 = *(const uint2*)(tab + (size_t)a1 * 16 + lane4 * 4);
    fma_mix2(f0, f1, v0.x, one);
    fma_mix2(f2, f3, v0.y, one);
    fma_mix2(g0, g1, v1.x, one);
    fma_mix2(g2, g3, v1.y, one);
  }
  if (e < e1) {
    uint2 v = *(const uint2*)(tab + (size_t)srcs[e] * 16 + lane4 * 4);
    fma_mix2(f0, f1, v.x, one);
    fma_mix2(f2, f3, v.y, one);
  }
  f0 += g0; f1 += g1; f2 += g2; f3 += g3;
}

// Sign-split aggregation: blockIdx%8 -> XCD (round-robin heuristic);
// XCDs 0-3 handle pos, 4-7 handle neg -> per-XCD gather table 3.2 MB < 4 MB L2.
// R10 structure: 64 nodes/block, 4 lanes/node. Writes raw dinv*acc (f32).
__global__ __launch_bounds__(256) void agg_split(
    const unsigned* __restrict__ srcP, const int* __restrict__ rowP,
    const unsigned* __restrict__ srcN, const int* __restrict__ rowN,
    const __half* __restrict__ inP, const __half* __restrict__ inN,
    const float* __restrict__ dinvP, const float* __restrict__ dinvN,
    float* __restrict__ tmpP, float* __restrict__ tmpN, int n)
{
  const int gb = blockIdx.x;
  const int xcd = gb & 7;
  const int sign = xcd >> 2;
  const int nblk = (gb >> 3) * 4 + (xcd & 3);
  const int lane4 = threadIdx.x & 3, grp = threadIdx.x >> 2;
  const int i = nblk * 64 + grp;
  if (i >= n) return;

  const unsigned* __restrict__ srcs = sign ? srcN : srcP;
  const int* __restrict__ row = sign ? rowN : rowP;
  const __half* __restrict__ tab = sign ? inN : inP;
  const float* __restrict__ dinv = sign ? dinvN : dinvP;
  float* __restrict__ tmp = sign ? tmpN : tmpP;

  const float one = 1.0f;
  float f0 = 0.f, f1 = 0.f, f2 = 0.f, f3 = 0.f;
  uint2 self = *(const uint2*)(tab + (size_t)i * 16 + lane4 * 4);
  fma_mix2(f0, f1, self.x, one);
  fma_mix2(f2, f3, self.y, one);
  seg_sum4(srcs, row[i], row[i + 1], tab, lane4, one, f0, f1, f2, f3);
  const float d = dinv[i];
  float4 o;
  o.x = f0 * d; o.y = f1 * d; o.z = f2 * d; o.w = f3 * d;
  *(float4*)(tmp + (size_t)i * 16 + lane4 * 4) = o;
}

// layer-1 combine: h = relu(b+tmpP) - relu(b+tmpN); G{p,n} = h*dinv fp16
// vectorized: one thread per 4 features (float4 in, half2x2 out)
__global__ __launch_bounds__(256) void combine1(
    const float* __restrict__ tmpP, const float* __restrict__ tmpN,
    const float* __restrict__ bp, const float* __restrict__ bn,
    const float* __restrict__ dinvP, const float* __restrict__ dinvN,
    __half* __restrict__ Gp, __half* __restrict__ Gn, int nq)
{
  int q = blockIdx.x * 256 + threadIdx.x;
  if (q >= nq) return;
  int i = q >> 2;
  float4 tp = ((const float4*)tmpP)[q];
  float4 tn = ((const float4*)tmpN)[q];
  float4 bpv = ((const float4*)bp)[q & 3];
  float4 bnv = ((const float4*)bn)[q & 3];
  float dp = dinvP[i], dn = dinvN[i];
  float h0 = fmaxf(bpv.x + tp.x, 0.f) - fmaxf(bnv.x + tn.x, 0.f);
  float h1 = fmaxf(bpv.y + tp.y, 0.f) - fmaxf(bnv.y + tn.y, 0.f);
  float h2 = fmaxf(bpv.z + tp.z, 0.f) - fmaxf(bnv.z + tn.z, 0.f);
  float h3 = fmaxf(bpv.w + tp.w, 0.f) - fmaxf(bnv.w + tn.w, 0.f);
  union { uint2 u; __half2 h[2]; } a, b;
  a.h[0] = __floats2half2_rn(h0 * dp, h1 * dp);
  a.h[1] = __floats2half2_rn(h2 * dp, h3 * dp);
  b.h[0] = __floats2half2_rn(h0 * dn, h1 * dn);
  b.h[1] = __floats2half2_rn(h2 * dn, h3 * dn);
  ((uint2*)Gp)[q] = a.u;
  ((uint2*)Gn)[q] = b.u;
}

// layer-2 epilogue: W2 GEMM + bias + relu-combine + log_softmax
__global__ __launch_bounds__(256) void final2(
    const float* __restrict__ Up, const float* __restrict__ Un,
    const float* __restrict__ W2p, const float* __restrict__ W2n,
    const float* __restrict__ b2p, const float* __restrict__ b2n,
    float* __restrict__ out, int n)
{
  __shared__ float wp[16 * 32], wn[16 * 32];
  for (int i = threadIdx.x; i < 512; i += 256) { wp[i] = W2p[i]; wn[i] = W2n[i]; }
  __syncthreads();

  const int tid = threadIdx.x;
  const int lane = tid & 15, grp = tid >> 4;
  const int i = blockIdx.x * 16 + grp;
  if (i >= n) return;

  float tp = Up[(size_t)i * 16 + lane];
  float tn = Un[(size_t)i * 16 + lane];

  float ap0 = b2p[lane], ap1 = b2p[lane + 16];
  float an0 = b2n[lane], an1 = b2n[lane + 16];
  #pragma unroll
  for (int k = 0; k < 16; ++k) {
    float tpk = __shfl(tp, k, 16);
    float tnk = __shfl(tn, k, 16);
    ap0 += tpk * wp[k * 32 + lane];
    ap1 += tpk * wp[k * 32 + lane + 16];
    an0 += tnk * wn[k * 32 + lane];
    an1 += tnk * wn[k * 32 + lane + 16];
  }
  float v0 = fmaxf(ap0, 0.f) - fmaxf(an0, 0.f);
  float v1 = fmaxf(ap1, 0.f) - fmaxf(an1, 0.f);
  float m = fmaxf(v0, v1);
  #pragma unroll
  for (int off = 8; off > 0; off >>= 1) m = fmaxf(m, __shfl_xor(m, off, 16));
  float s = __expf(v0 - m) + __expf(v1 - m);
  #pragma unroll
  for (int off = 8; off > 0; off >>= 1) s += __shfl_xor(s, off, 16);
  float ls = __logf(s);
  out[(size_t)i * 32 + lane] = v0 - m - ls;
  out[(size_t)i * 32 + lane + 16] = v1 - m - ls;
}

extern "C" void kernel_launch(void* const* d_in, const int* in_sizes, int n_in,
                              void* d_out, int out_size, void* d_ws, size_t ws_size,
                              hipStream_t stream) {
  const float* x   = (const float*)d_in[0];
  const int*   eP  = (const int*)d_in[1];
  const int*   eN  = (const int*)d_in[2];
  const float* W1p = (const float*)d_in[3];
  const float* b1p = (const float*)d_in[4];
  const float* W1n = (const float*)d_in[5];
  const float* b1n = (const float*)d_in[6];
  const float* W2p = (const float*)d_in[7];
  const float* b2p = (const float*)d_in[8];
  const float* W2n = (const float*)d_in[9];
  const float* b2n = (const float*)d_in[10];
  float* out = (float*)d_out;

  const int HID = in_sizes[4];             // 16
  const int F   = in_sizes[3] / HID;       // 128
  const int n   = in_sizes[0] / F;         // 100000
  const int E   = in_sizes[1] / 2;         // 3,200,000
  (void)out_size; (void)n_in; (void)ws_size;

  const int NBK = (n + BSZ - 1) >> BSHIFT;                 // 391
  const int CH  = (((E + 511) / 512) + 3) & ~3;            // 6252 (mult of 4)
  const int NCH = (E + CH - 1) / CH;                       // 512 (mult of 8)

  char* p = (char*)d_ws;
  auto alloc = [&](size_t bytes) { char* r = p; p += (bytes + 255) & ~(size_t)255; return r; };

  int*      ccP   = (int*)alloc((size_t)NCH * NBK * 4);
  int*      ccN   = (int*)alloc((size_t)NCH * NBK * 4);
  int*      totP  = (int*)alloc((size_t)NBK * 4);
  int*      totN  = (int*)alloc((size_t)NBK * 4);
  unsigned* prP   = (unsigned*)alloc((size_t)E * 4);
  unsigned* prN   = (unsigned*)alloc((size_t)E * 4);
  unsigned* srcP  = (unsigned*)alloc((size_t)E * 4);
  unsigned* srcN  = (unsigned*)alloc((size_t)E * 4);
  int*      rowP  = (int*)alloc((size_t)(n + 1) * 4);
  int*      rowN  = (int*)alloc((size_t)(n + 1) * 4);
  float*    dinvP = (float*)alloc((size_t)n * 4);
  float*    dinvN = (float*)alloc((size_t)n * 4);
  __half*   hsP   = (__half*)alloc((size_t)n * 16 * 2);
  __half*   hsN   = (__half*)alloc((size_t)n * 16 * 2);
  __half*   Gp    = (__half*)alloc((size_t)n * 16 * 2);
  __half*   Gn    = (__half*)alloc((size_t)n * 16 * 2);
  float*    tmpP  = (float*)alloc((size_t)n * 16 * 4);
  float*    tmpN  = (float*)alloc((size_t)n * 16 * 4);

  // ---- bucketed, dst-sorted edge build (both signs fused per launch) ----
  hipLaunchKernelGGL(bucket_count2, dim3(NCH, 2), dim3(256), 0, stream,
                     eP, eN, E, CH, NCH, NBK, ccP, ccN);
  hipLaunchKernelGGL(col_scan2, dim3(NBK, 2), dim3(512), 0, stream,
                     ccP, ccN, NCH, NBK, totP, totN);
  hipLaunchKernelGGL(bucket_fill3, dim3(NCH, 2), dim3(512), 0, stream,
                     eP, eN, E, CH, NCH, NBK, ccP, ccN, totP, totN, prP, prN);
  hipLaunchKernelGGL(tile_sort3, dim3(NBK, 2), dim3(256), 0, stream,
                     prP, prN, totP, totN, n, E, dinvP, dinvN, rowP, rowN, srcP, srcN);

  // grids: xw1/final2 use 16 rows/block; agg uses 64 nodes/block (R10)
  const int NB16 = (n + 15) / 16;                 // 6250
  const int NB64 = (n + 63) / 64;                 // 1563
  const int NBS  = ((NB64 + 3) / 4) * 4;          // 1564
  const int GRID = NBS * 2;                       // 3128 (multiple of 8)

  // ---- layer 1 ----
  hipLaunchKernelGGL(xw1_kernel, dim3(NB16), dim3(256), 0, stream,
                     x, W1p, W1n, dinvP, dinvN, hsP, hsN, n);
  hipLaunchKernelGGL(agg_split, dim3(GRID), dim3(256), 0, stream,
                     srcP, rowP, srcN, rowN, hsP, hsN, dinvP, dinvN, tmpP, tmpN, n);
  hipLaunchKernelGGL(combine1, dim3((n * 4 + 255) / 256), dim3(256), 0, stream,
                     tmpP, tmpN, b1p, b1n, dinvP, dinvN, Gp, Gn, n * 4);

  // ---- layer 2 ----
  hipLaunchKernelGGL(agg_split, dim3(GRID), dim3(256), 0, stream,
                     srcP, rowP, srcN, rowN, Gp, Gn, dinvP, dinvN, tmpP, tmpN, n);
  hipLaunchKernelGGL(final2, dim3(NB16), dim3(256), 0, stream,
                     tmpP, tmpN, W2p, W2n, b2p, b2n, out, n);
}